// Round 8
// baseline (475.778 us; speedup 1.0000x reference)
//
#include <hip/hip_runtime.h>
#include <hip/hip_fp16.h>

#define HH 384
#define WW 384
#define HWSZ (HH*WW)   // 147456
#define NB 4

typedef _Float16 f16x8 __attribute__((ext_vector_type(8)));
typedef float    f32x4 __attribute__((ext_vector_type(4)));

// ---- ws layout (bytes) ----
// h2 fp16 NHWC [4][384][384][64]: 75,497,472 B @ 0
#define W1T_B 75497472u               // [36][64] f32, 9216 B
#define W2F_B (W1T_B + 9216u)         // [2][9][4][64][8] f16, 73728 B  (B-frag order)
#define W3F_B (W2F_B + 73728u)        // [2][9][6][64][8] f16, 110592 B (B-frag order, co pad 96)
// total 75,691,008 B ~= 72.2 MiB (proven safe)

// ---- prep: w1 transpose (f32) + w2/w3 packed into MFMA B-fragment order (f16) ----
// B-frag for 16x16x32: lane l supplies B[k=(l>>4)*8+j][n=l&15]; frag = 64 lanes x 8 halfs.
__global__ __launch_bounds__(256) void prep(const float* __restrict__ w1,
    const float* __restrict__ w2, const float* __restrict__ w3, char* __restrict__ ws) {
  int i = blockIdx.x * 256 + threadIdx.x;
  float* w1T = (float*)(ws + W1T_B);
  _Float16* w2f = (_Float16*)(ws + W2F_B);
  _Float16* w3f = (_Float16*)(ws + W3F_B);
  if (i < 2304) { int co = i & 63, row = i >> 6; w1T[i] = w1[co * 36 + row]; return; }
  int o = i - 2304;
  if (o < 36864) {  // w2f: [cc][tap][cj][lane][j] strides 18432/2048/512/8/1
    int cc = o / 18432, rem = o % 18432;
    int tap = rem >> 11, r2 = rem & 2047;
    int cj = r2 >> 9, l = (r2 >> 3) & 63, j = r2 & 7;
    int co = cj * 16 + (l & 15);
    int ci = cc * 32 + (l >> 4) * 8 + j;
    w2f[o] = (_Float16)w2[co * 576 + ci * 9 + tap];
    return;
  }
  o -= 36864;
  if (o < 55296) {  // w3f: [cc][tap][cj][lane][j] strides 27648/3072/512/8/1
    int cc = o / 27648, rem = o % 27648;
    int tap = rem / 3072, r2 = rem % 3072;
    int cj = r2 >> 9, l = (r2 >> 3) & 63, j = r2 & 7;
    int co = cj * 16 + (l & 15);
    int ci = cc * 32 + (l >> 4) * 8 + j;
    w3f[o] = (co < 81) ? (_Float16)w3[co * 576 + ci * 9 + tap] : (_Float16)0.f;
  }
}

// ---- stage 1: fused conv1 (VALU) + conv2 (MFMA) -> h2 fp16 NHWC ----
// block = 16x16 px, 256 thr = 4 waves; wave w owns output rows w*4..w*4+3, all 64 co.
// B-frags come straight from global (L2-resident, coalesced) — no weight LDS.
__global__ __launch_bounds__(256, 4) void conv12(
    const float* __restrict__ rgb, const float* __restrict__ depth,
    const float* __restrict__ b1, const float* __restrict__ b2,
    const char* __restrict__ wsro, unsigned short* __restrict__ h2) {
  __shared__ __align__(16) char smem[36864];
  float*    xw  = (float*)smem;                 // 6400 B  [4][20][20] origin (-2,-2)
  _Float16* h1T = (_Float16*)(smem + 6400);     // 20736 B [18*18][32] swizzled
  _Float16* tr  = (_Float16*)smem;              // epilogue alias: [16][16][72] = 36864 B
  const int t = threadIdx.x;
  const int x0 = blockIdx.x * 16, y0 = blockIdx.y * 16, b = blockIdx.z;
  const float* w1T = (const float*)(wsro + W1T_B);
  const _Float16* w2f = (const _Float16*)(wsro + W2F_B);
  const int lane = t & 63, q = lane >> 4, n = lane & 15, w = t >> 6;

  // stage input tile
  for (int idx = t; idx < 1600; idx += 256) {
    int ci = idx / 400, r2 = idx % 400, iy = r2 / 20, ix = r2 % 20;
    int gy = y0 + iy - 2, gx = x0 + ix - 2;
    float v = 0.f;
    if ((unsigned)gy < (unsigned)HH && (unsigned)gx < (unsigned)WW)
      v = (ci < 3) ? rgb[(size_t)(b * 3 + ci) * HWSZ + gy * WW + gx]
                   : depth[(size_t)b * HWSZ + gy * WW + gx];
    xw[idx] = v;
  }

  f32x4 acc[4][4];
  #pragma unroll
  for (int cj = 0; cj < 4; ++cj) {
    float bv = b2[cj * 16 + n];
    #pragma unroll
    for (int ri = 0; ri < 4; ++ri) acc[ri][cj] = (f32x4){bv, bv, bv, bv};
  }
  __syncthreads();

  // conv1 work split (balanced): wave w computes co-half h=w>>1 (wave-uniform ->
  // weight reads stay scalar) for px range [(w&1)*162, +162) of the 18x18 halo.
  const int h1h = w >> 1;              // co-half within ci-chunk (0/1)
  const int pxb = (w & 1) * 162;       // px base for this wave

  for (int cc = 0; cc < 2; ++cc) {
    // conv1: h1 co-chunk [cc*32+h1h*16, +16). OOB positions MUST be zero.
    #pragma unroll 1
    for (int p = 0; p < 3; ++p) {
      int rel = p * 64 + lane;
      if (rel < 162) {
        int px = pxb + rel;
        int row = px / 18, col = px % 18;
        bool ok = ((unsigned)(y0 + row - 1) < (unsigned)HH) &&
                  ((unsigned)(x0 + col - 1) < (unsigned)WW);
        float a1[16];
        #pragma unroll
        for (int k = 0; k < 16; ++k) a1[k] = b1[cc * 32 + h1h * 16 + k];
        #pragma unroll 1
        for (int ci = 0; ci < 4; ++ci) {
          #pragma unroll 1
          for (int ky = 0; ky < 3; ++ky) {
            const float* xp = &xw[ci * 400 + (row + ky) * 20 + col];
            float xv[3] = {xp[0], xp[1], xp[2]};
            #pragma unroll
            for (int kx = 0; kx < 3; ++kx) {
              const float* wr = w1T + (ci * 9 + ky * 3 + kx) * 64 + cc * 32 + h1h * 16;
              #pragma unroll
              for (int k = 0; k < 16; ++k) a1[k] = fmaf(xv[kx], wr[k], a1[k]);
            }
          }
        }
        int base = (row * 18 + col) * 32, sw = col & 3;
        #pragma unroll
        for (int g2 = 0; g2 < 2; ++g2) {
          int g = h1h * 2 + g2;
          f16x8 hv;
          #pragma unroll
          for (int j = 0; j < 8; ++j)
            hv[j] = ok ? (_Float16)fmaxf(a1[g2 * 8 + j], 0.f) : (_Float16)0.f;
          *(f16x8*)&h1T[base + ((g ^ sw) * 8)] = hv;
        }
      }
    }
    __syncthreads();

    // conv2 MFMA: 9 taps x (4 A ds_reads + 4 B global loads -> 16 MFMA)
    #pragma unroll 1
    for (int tap = 0; tap < 9; ++tap) {
      int ty = tap / 3, tx = tap % 3;
      f16x8 af[4];
      #pragma unroll
      for (int ri = 0; ri < 4; ++ri) {
        int row = w * 4 + ri + ty;           // 0..17
        int col = n + tx;                    // A-frag m = lane&15 = x
        af[ri] = *(const f16x8*)&h1T[(row * 18 + col) * 32 + ((q ^ (col & 3)) * 8)];
      }
      #pragma unroll
      for (int cj = 0; cj < 4; ++cj) {
        f16x8 bf = *(const f16x8*)&w2f[cc * 18432 + tap * 2048 + cj * 512 + lane * 8];
        #pragma unroll
        for (int ri = 0; ri < 4; ++ri)
          acc[ri][cj] = __builtin_amdgcn_mfma_f32_16x16x32_f16(af[ri], bf, acc[ri][cj], 0, 0, 0);
      }
    }
    __syncthreads();
  }

  // epilogue: ReLU + fp16, transpose via LDS (tr aliases everything), NHWC store.
  // D layout: x = q*4+i, co = cj*16+n, y = w*4+ri.
  #pragma unroll
  for (int ri = 0; ri < 4; ++ri) {
    int py = w * 4 + ri;
    #pragma unroll
    for (int cj = 0; cj < 4; ++cj)
      #pragma unroll
      for (int i = 0; i < 4; ++i)
        tr[(py * 16 + q * 4 + i) * 72 + cj * 16 + n] = (_Float16)fmaxf(acc[ri][cj][i], 0.f);
  }
  __syncthreads();
  #pragma unroll
  for (int k = 0; k < 8; ++k) {
    int idx = t + k * 256;                     // [0,2048): y | x | c8
    int y = idx >> 7, x = (idx >> 3) & 15, c8 = (idx & 7) * 8;
    f16x8 v = *(const f16x8*)&tr[(y * 16 + x) * 72 + c8];
    *(f16x8*)&h2[(((size_t)b * HH + y0 + y) * WW + x0 + x) * 64 + c8] = v;
  }
}

// ---- stage 2: conv3 (MFMA, co 81->96) + in-wave softmax + bokeh ----
// block = 16x16 px, 512 thr = 8 waves; wave w owns rows 2w..2w+1 (acc[2][6] = 48 VGPR).
// NOTE: every loop touching acc[][] must be FULLY UNROLLED — a runtime index on
// acc demotes it to scratch (R6: 1.5 GB of scratch churn from `#pragma unroll 1`).
// B-frags straight from global (L2-resident) — no weight LDS, 2 barriers per chunk.
__global__ __launch_bounds__(512, 4) void conv3bokeh(
    const unsigned short* __restrict__ h2, const float* __restrict__ rgb,
    const float* __restrict__ b3, const char* __restrict__ wsro,
    float* __restrict__ out) {
  __shared__ __align__(16) char smem[27648];
  _Float16* h2T  = (_Float16*)smem;             // 20736 B [18*18][32] swizzled
  float*    rgbl = (float*)(smem + 20736);      // 6912 B  [3][24][24] origin (-4,-4)
  const int t = threadIdx.x;
  const int x0 = blockIdx.x * 16, y0 = blockIdx.y * 16, b = blockIdx.z;
  const _Float16* w3f = (const _Float16*)(wsro + W3F_B);
  const int lane = t & 63, q = lane >> 4, n = lane & 15, w = t >> 6;

  f32x4 acc[2][6];
  #pragma unroll
  for (int cj = 0; cj < 6; ++cj) {
    int tap = cj * 16 + n;
    float bv = (tap < 81) ? b3[tap] : 0.f;
    acc[0][cj] = (f32x4){bv, bv, bv, bv};
    acc[1][cj] = (f32x4){bv, bv, bv, bv};
  }
  // stage rgb tile
  for (int idx = t; idx < 1728; idx += 512) {
    int c = idx / 576, r2 = idx % 576, ry = r2 / 24, rx = r2 % 24;
    int gy = y0 + ry - 4, gx = x0 + rx - 4;
    float v = 0.f;
    if ((unsigned)gy < (unsigned)HH && (unsigned)gx < (unsigned)WW)
      v = rgb[(size_t)(b * 3 + c) * HWSZ + gy * WW + gx];
    rgbl[idx] = v;
  }

  for (int cc = 0; cc < 2; ++cc) {
    // stage h2T chunk from NHWC h2: 16B-aligned coalesced f16x8 loads, zero-padded.
    for (int idx = t; idx < 1296; idx += 512) {
      int g = idx & 3, pc = idx >> 2;
      int row = pc / 18, col = pc % 18;
      int gy = y0 + row - 1, gx = x0 + col - 1;
      f16x8 v = {};
      if ((unsigned)gy < (unsigned)HH && (unsigned)gx < (unsigned)WW)
        v = *(const f16x8*)&h2[(((size_t)b * HH + gy) * WW + gx) * 64 + cc * 32 + g * 8];
      *(f16x8*)&h2T[(row * 18 + col) * 32 + ((g ^ (col & 3)) * 8)] = v;
    }
    __syncthreads();

    #pragma unroll 1
    for (int tap = 0; tap < 9; ++tap) {
      int ty = tap / 3, tx = tap % 3;
      f16x8 af[2];
      #pragma unroll
      for (int ri = 0; ri < 2; ++ri) {
        int row = w * 2 + ri + ty;           // 0..17
        int col = n + tx;
        af[ri] = *(const f16x8*)&h2T[(row * 18 + col) * 32 + ((q ^ (col & 3)) * 8)];
      }
      #pragma unroll
      for (int cj = 0; cj < 6; ++cj) {
        f16x8 bf = *(const f16x8*)&w3f[cc * 27648 + tap * 3072 + cj * 512 + lane * 8];
        acc[0][cj] = __builtin_amdgcn_mfma_f32_16x16x32_f16(af[0], bf, acc[0][cj], 0, 0, 0);
        acc[1][cj] = __builtin_amdgcn_mfma_f32_16x16x32_f16(af[1], bf, acc[1][cj], 0, 0, 0);
      }
    }
    __syncthreads();   // protects h2T before next-chunk overwrite
  }

  // epilogue: per-pixel softmax over 81 taps (lanes n=0..15 x cj=0..5) + bokeh gather.
  // FULLY unrolled over ri (see note above).
  int tyj[6], txj[6]; float vm[6];
  #pragma unroll
  for (int cj = 0; cj < 6; ++cj) {
    int tap = cj * 16 + n;
    tyj[cj] = tap / 9; txj[cj] = tap % 9;
    vm[cj] = (tap < 81) ? 1.f : 0.f;
  }
  #pragma unroll
  for (int ri = 0; ri < 2; ++ri) {
    int ry0 = w * 2 + ri;
    float mx[4];
    #pragma unroll
    for (int i = 0; i < 4; ++i) {
      float m = -1e30f;
      #pragma unroll
      for (int cj = 0; cj < 6; ++cj)
        m = fmaxf(m, vm[cj] > 0.f ? acc[ri][cj][i] : -1e30f);
      mx[i] = m;
    }
    #pragma unroll
    for (int st = 1; st < 16; st <<= 1)
      #pragma unroll
      for (int i = 0; i < 4; ++i) mx[i] = fmaxf(mx[i], __shfl_xor(mx[i], st));
    float s[4] = {0, 0, 0, 0}, a0[4] = {0, 0, 0, 0}, a1[4] = {0, 0, 0, 0}, a2[4] = {0, 0, 0, 0};
    #pragma unroll
    for (int cj = 0; cj < 6; ++cj) {
      int ry = ry0 + tyj[cj];
      #pragma unroll
      for (int i = 0; i < 4; ++i) {
        float e = vm[cj] * __expf(acc[ri][cj][i] - mx[i]);
        s[i] += e;
        int rx = q * 4 + i + txj[cj];
        a0[i] = fmaf(e, rgbl[ry * 24 + rx], a0[i]);
        a1[i] = fmaf(e, rgbl[576 + ry * 24 + rx], a1[i]);
        a2[i] = fmaf(e, rgbl[1152 + ry * 24 + rx], a2[i]);
      }
    }
    #pragma unroll
    for (int st = 1; st < 16; st <<= 1)
      #pragma unroll
      for (int i = 0; i < 4; ++i) {
        s[i] += __shfl_xor(s[i], st);
        a0[i] += __shfl_xor(a0[i], st);
        a1[i] += __shfl_xor(a1[i], st);
        a2[i] += __shfl_xor(a2[i], st);
      }
    if (n == 0) {
      int y = y0 + ry0;
      #pragma unroll
      for (int i = 0; i < 4; ++i) {
        int x = x0 + q * 4 + i;
        float inv = 1.f / s[i];
        size_t o = (size_t)b * 3 * HWSZ + (size_t)y * WW + x;
        out[o] = a0[i] * inv;
        out[o + HWSZ] = a1[i] * inv;
        out[o + 2 * HWSZ] = a2[i] * inv;
      }
    }
  }
}

extern "C" void kernel_launch(void* const* d_in, const int* in_sizes, int n_in,
                              void* d_out, int out_size, void* d_ws, size_t ws_size,
                              hipStream_t stream) {
  const float* rgb   = (const float*)d_in[0];
  const float* depth = (const float*)d_in[1];
  const float* w1    = (const float*)d_in[2];
  const float* b1    = (const float*)d_in[3];
  const float* w2    = (const float*)d_in[4];
  const float* b2    = (const float*)d_in[5];
  const float* w3    = (const float*)d_in[6];
  const float* b3    = (const float*)d_in[7];
  char* ws = (char*)d_ws;
  unsigned short* h2 = (unsigned short*)d_ws;
  float* out = (float*)d_out;

  prep<<<369, 256, 0, stream>>>(w1, w2, w3, ws);

  dim3 grid(WW / 16, HH / 16, NB);  // 24 x 24 x 4
  conv12<<<grid, 256, 0, stream>>>(rgb, depth, b1, b2, ws, h2);
  conv3bokeh<<<grid, 512, 0, stream>>>(h2, rgb, b3, ws, out);
}

// Round 9
// 451.595 us; speedup vs baseline: 1.0536x; 1.0536x over previous
//
#include <hip/hip_runtime.h>
#include <hip/hip_fp16.h>

#define HH 384
#define WW 384
#define HWSZ (HH*WW)   // 147456
#define NB 4

typedef _Float16 f16x8 __attribute__((ext_vector_type(8)));
typedef float    f32x4 __attribute__((ext_vector_type(4)));

// ---- ws layout (bytes) ----
// h2 fp16 NHWC [4][384][384][64]: 75,497,472 B @ 0
#define W1T_B 75497472u               // [36][64] f32, 9216 B
#define W2F_B (W1T_B + 9216u)         // [2][9][4][64][8] f16, 73728 B  (B-frag order)
#define W3F_B (W2F_B + 73728u)        // [2][9][6][64][8] f16, 110592 B (B-frag order, co pad 96)
// total 75,691,008 B ~= 72.2 MiB (proven safe)

// ---- prep: w1 transpose (f32) + w2/w3 packed into MFMA B-fragment order (f16) ----
// B-frag for 16x16x32: lane l supplies B[k=(l>>4)*8+j][n=l&15]; frag = 64 lanes x 8 halfs.
__global__ __launch_bounds__(256) void prep(const float* __restrict__ w1,
    const float* __restrict__ w2, const float* __restrict__ w3, char* __restrict__ ws) {
  int i = blockIdx.x * 256 + threadIdx.x;
  float* w1T = (float*)(ws + W1T_B);
  _Float16* w2f = (_Float16*)(ws + W2F_B);
  _Float16* w3f = (_Float16*)(ws + W3F_B);
  if (i < 2304) { int co = i & 63, row = i >> 6; w1T[i] = w1[co * 36 + row]; return; }
  int o = i - 2304;
  if (o < 36864) {  // w2f: [cc][tap][cj][lane][j] strides 18432/2048/512/8/1
    int cc = o / 18432, rem = o % 18432;
    int tap = rem >> 11, r2 = rem & 2047;
    int cj = r2 >> 9, l = (r2 >> 3) & 63, j = r2 & 7;
    int co = cj * 16 + (l & 15);
    int ci = cc * 32 + (l >> 4) * 8 + j;
    w2f[o] = (_Float16)w2[co * 576 + ci * 9 + tap];
    return;
  }
  o -= 36864;
  if (o < 55296) {  // w3f: [cc][tap][cj][lane][j] strides 27648/3072/512/8/1
    int cc = o / 27648, rem = o % 27648;
    int tap = rem / 3072, r2 = rem % 3072;
    int cj = r2 >> 9, l = (r2 >> 3) & 63, j = r2 & 7;
    int co = cj * 16 + (l & 15);
    int ci = cc * 32 + (l >> 4) * 8 + j;
    w3f[o] = (co < 81) ? (_Float16)w3[co * 576 + ci * 9 + tap] : (_Float16)0.f;
  }
}

// ---- stage 1: fused conv1 (VALU) + conv2 (MFMA) -> h2 fp16 NHWC ----
// block = 16x16 px, 256 thr = 4 waves; wave w owns output rows w*4..w*4+3, all 64 co.
// B-frags come straight from global (L2-resident, coalesced) — no weight LDS.
// NO min-waves clause: R8's (256,4) capped VGPR at 64 -> 105 MB of scratch spill.
__global__ __launch_bounds__(256) void conv12(
    const float* __restrict__ rgb, const float* __restrict__ depth,
    const float* __restrict__ b1, const float* __restrict__ b2,
    const char* __restrict__ wsro, unsigned short* __restrict__ h2) {
  __shared__ __align__(16) char smem[36864];
  float*    xw  = (float*)smem;                 // 6400 B  [4][20][20] origin (-2,-2)
  _Float16* h1T = (_Float16*)(smem + 6400);     // 20736 B [18*18][32] swizzled
  _Float16* tr  = (_Float16*)smem;              // epilogue alias: [16][16][72] = 36864 B
  const int t = threadIdx.x;
  const int x0 = blockIdx.x * 16, y0 = blockIdx.y * 16, b = blockIdx.z;
  const float* w1T = (const float*)(wsro + W1T_B);
  const _Float16* w2f = (const _Float16*)(wsro + W2F_B);
  const int lane = t & 63, q = lane >> 4, n = lane & 15, w = t >> 6;

  // stage input tile
  for (int idx = t; idx < 1600; idx += 256) {
    int ci = idx / 400, r2 = idx % 400, iy = r2 / 20, ix = r2 % 20;
    int gy = y0 + iy - 2, gx = x0 + ix - 2;
    float v = 0.f;
    if ((unsigned)gy < (unsigned)HH && (unsigned)gx < (unsigned)WW)
      v = (ci < 3) ? rgb[(size_t)(b * 3 + ci) * HWSZ + gy * WW + gx]
                   : depth[(size_t)b * HWSZ + gy * WW + gx];
    xw[idx] = v;
  }

  f32x4 acc[4][4];
  #pragma unroll
  for (int cj = 0; cj < 4; ++cj) {
    float bv = b2[cj * 16 + n];
    #pragma unroll
    for (int ri = 0; ri < 4; ++ri) acc[ri][cj] = (f32x4){bv, bv, bv, bv};
  }
  __syncthreads();

  // conv1 work split (balanced): wave w computes co-half h=w>>1 (wave-uniform ->
  // weight reads stay scalar) for px range [(w&1)*162, +162) of the 18x18 halo.
  const int h1h = w >> 1;              // co-half within ci-chunk (0/1)
  const int pxb = (w & 1) * 162;       // px base for this wave

  for (int cc = 0; cc < 2; ++cc) {
    // conv1: h1 co-chunk [cc*32+h1h*16, +16). OOB positions MUST be zero.
    #pragma unroll 1
    for (int p = 0; p < 3; ++p) {
      int rel = p * 64 + lane;
      if (rel < 162) {
        int px = pxb + rel;
        int row = px / 18, col = px % 18;
        bool ok = ((unsigned)(y0 + row - 1) < (unsigned)HH) &&
                  ((unsigned)(x0 + col - 1) < (unsigned)WW);
        float a1[16];
        #pragma unroll
        for (int k = 0; k < 16; ++k) a1[k] = b1[cc * 32 + h1h * 16 + k];
        #pragma unroll 1
        for (int ci = 0; ci < 4; ++ci) {
          #pragma unroll 1
          for (int ky = 0; ky < 3; ++ky) {
            const float* xp = &xw[ci * 400 + (row + ky) * 20 + col];
            float xv[3] = {xp[0], xp[1], xp[2]};
            #pragma unroll
            for (int kx = 0; kx < 3; ++kx) {
              const float* wr = w1T + (ci * 9 + ky * 3 + kx) * 64 + cc * 32 + h1h * 16;
              #pragma unroll
              for (int k = 0; k < 16; ++k) a1[k] = fmaf(xv[kx], wr[k], a1[k]);
            }
          }
        }
        int base = (row * 18 + col) * 32, sw = col & 3;
        #pragma unroll
        for (int g2 = 0; g2 < 2; ++g2) {
          int g = h1h * 2 + g2;
          f16x8 hv;
          #pragma unroll
          for (int j = 0; j < 8; ++j)
            hv[j] = ok ? (_Float16)fmaxf(a1[g2 * 8 + j], 0.f) : (_Float16)0.f;
          *(f16x8*)&h1T[base + ((g ^ sw) * 8)] = hv;
        }
      }
    }
    __syncthreads();

    // conv2 MFMA: 9 taps x (4 A ds_reads + 4 B global loads -> 16 MFMA)
    #pragma unroll 1
    for (int tap = 0; tap < 9; ++tap) {
      int ty = tap / 3, tx = tap % 3;
      f16x8 af[4];
      #pragma unroll
      for (int ri = 0; ri < 4; ++ri) {
        int row = w * 4 + ri + ty;           // 0..17
        int col = n + tx;                    // A-frag m = lane&15 = x
        af[ri] = *(const f16x8*)&h1T[(row * 18 + col) * 32 + ((q ^ (col & 3)) * 8)];
      }
      #pragma unroll
      for (int cj = 0; cj < 4; ++cj) {
        f16x8 bf = *(const f16x8*)&w2f[cc * 18432 + tap * 2048 + cj * 512 + lane * 8];
        #pragma unroll
        for (int ri = 0; ri < 4; ++ri)
          acc[ri][cj] = __builtin_amdgcn_mfma_f32_16x16x32_f16(af[ri], bf, acc[ri][cj], 0, 0, 0);
      }
    }
    __syncthreads();
  }

  // epilogue: ReLU + fp16, transpose via LDS (tr aliases everything), NHWC store.
  // D layout: x = q*4+i, co = cj*16+n, y = w*4+ri.
  #pragma unroll
  for (int ri = 0; ri < 4; ++ri) {
    int py = w * 4 + ri;
    #pragma unroll
    for (int cj = 0; cj < 4; ++cj)
      #pragma unroll
      for (int i = 0; i < 4; ++i)
        tr[(py * 16 + q * 4 + i) * 72 + cj * 16 + n] = (_Float16)fmaxf(acc[ri][cj][i], 0.f);
  }
  __syncthreads();
  #pragma unroll
  for (int k = 0; k < 8; ++k) {
    int idx = t + k * 256;                     // [0,2048): y | x | c8
    int y = idx >> 7, x = (idx >> 3) & 15, c8 = (idx & 7) * 8;
    f16x8 v = *(const f16x8*)&tr[(y * 16 + x) * 72 + c8];
    *(f16x8*)&h2[(((size_t)b * HH + y0 + y) * WW + x0 + x) * 64 + c8] = v;
  }
}

// ---- stage 2: conv3 (MFMA, co 81->96) + in-wave softmax + bokeh ----
// block = 16x16 px, 512 thr = 8 waves; wave w owns rows 2w..2w+1 (acc[2][6] = 48 VGPR).
// NOTE: every loop touching acc[][] must be FULLY UNROLLED — a runtime index on
// acc demotes it to scratch (R6: 1.5 GB of scratch churn from `#pragma unroll 1`).
// B-frags straight from global (L2-resident) — no weight LDS, 2 barriers per chunk.
// NO min-waves clause (R8 lesson: register caps cause scratch spill).
__global__ __launch_bounds__(512) void conv3bokeh(
    const unsigned short* __restrict__ h2, const float* __restrict__ rgb,
    const float* __restrict__ b3, const char* __restrict__ wsro,
    float* __restrict__ out) {
  __shared__ __align__(16) char smem[27648];
  _Float16* h2T  = (_Float16*)smem;             // 20736 B [18*18][32] swizzled
  float*    rgbl = (float*)(smem + 20736);      // 6912 B  [3][24][24] origin (-4,-4)
  const int t = threadIdx.x;
  const int x0 = blockIdx.x * 16, y0 = blockIdx.y * 16, b = blockIdx.z;
  const _Float16* w3f = (const _Float16*)(wsro + W3F_B);
  const int lane = t & 63, q = lane >> 4, n = lane & 15, w = t >> 6;

  f32x4 acc[2][6];
  #pragma unroll
  for (int cj = 0; cj < 6; ++cj) {
    int tap = cj * 16 + n;
    float bv = (tap < 81) ? b3[tap] : 0.f;
    acc[0][cj] = (f32x4){bv, bv, bv, bv};
    acc[1][cj] = (f32x4){bv, bv, bv, bv};
  }
  // stage rgb tile
  for (int idx = t; idx < 1728; idx += 512) {
    int c = idx / 576, r2 = idx % 576, ry = r2 / 24, rx = r2 % 24;
    int gy = y0 + ry - 4, gx = x0 + rx - 4;
    float v = 0.f;
    if ((unsigned)gy < (unsigned)HH && (unsigned)gx < (unsigned)WW)
      v = rgb[(size_t)(b * 3 + c) * HWSZ + gy * WW + gx];
    rgbl[idx] = v;
  }

  for (int cc = 0; cc < 2; ++cc) {
    // stage h2T chunk from NHWC h2: 16B-aligned coalesced f16x8 loads, zero-padded.
    for (int idx = t; idx < 1296; idx += 512) {
      int g = idx & 3, pc = idx >> 2;
      int row = pc / 18, col = pc % 18;
      int gy = y0 + row - 1, gx = x0 + col - 1;
      f16x8 v = {};
      if ((unsigned)gy < (unsigned)HH && (unsigned)gx < (unsigned)WW)
        v = *(const f16x8*)&h2[(((size_t)b * HH + gy) * WW + gx) * 64 + cc * 32 + g * 8];
      *(f16x8*)&h2T[(row * 18 + col) * 32 + ((g ^ (col & 3)) * 8)] = v;
    }
    __syncthreads();

    #pragma unroll 1
    for (int tap = 0; tap < 9; ++tap) {
      int ty = tap / 3, tx = tap % 3;
      f16x8 af[2];
      #pragma unroll
      for (int ri = 0; ri < 2; ++ri) {
        int row = w * 2 + ri + ty;           // 0..17
        int col = n + tx;
        af[ri] = *(const f16x8*)&h2T[(row * 18 + col) * 32 + ((q ^ (col & 3)) * 8)];
      }
      #pragma unroll
      for (int cj = 0; cj < 6; ++cj) {
        f16x8 bf = *(const f16x8*)&w3f[cc * 27648 + tap * 3072 + cj * 512 + lane * 8];
        acc[0][cj] = __builtin_amdgcn_mfma_f32_16x16x32_f16(af[0], bf, acc[0][cj], 0, 0, 0);
        acc[1][cj] = __builtin_amdgcn_mfma_f32_16x16x32_f16(af[1], bf, acc[1][cj], 0, 0, 0);
      }
    }
    __syncthreads();   // protects h2T before next-chunk overwrite
  }

  // epilogue: per-pixel softmax over 81 taps (lanes n=0..15 x cj=0..5) + bokeh gather.
  // FULLY unrolled over ri (see note above).
  int tyj[6], txj[6]; float vm[6];
  #pragma unroll
  for (int cj = 0; cj < 6; ++cj) {
    int tap = cj * 16 + n;
    tyj[cj] = tap / 9; txj[cj] = tap % 9;
    vm[cj] = (tap < 81) ? 1.f : 0.f;
  }
  #pragma unroll
  for (int ri = 0; ri < 2; ++ri) {
    int ry0 = w * 2 + ri;
    float mx[4];
    #pragma unroll
    for (int i = 0; i < 4; ++i) {
      float m = -1e30f;
      #pragma unroll
      for (int cj = 0; cj < 6; ++cj)
        m = fmaxf(m, vm[cj] > 0.f ? acc[ri][cj][i] : -1e30f);
      mx[i] = m;
    }
    #pragma unroll
    for (int st = 1; st < 16; st <<= 1)
      #pragma unroll
      for (int i = 0; i < 4; ++i) mx[i] = fmaxf(mx[i], __shfl_xor(mx[i], st));
    float s[4] = {0, 0, 0, 0}, a0[4] = {0, 0, 0, 0}, a1[4] = {0, 0, 0, 0}, a2[4] = {0, 0, 0, 0};
    #pragma unroll
    for (int cj = 0; cj < 6; ++cj) {
      int ry = ry0 + tyj[cj];
      #pragma unroll
      for (int i = 0; i < 4; ++i) {
        float e = vm[cj] * __expf(acc[ri][cj][i] - mx[i]);
        s[i] += e;
        int rx = q * 4 + i + txj[cj];
        a0[i] = fmaf(e, rgbl[ry * 24 + rx], a0[i]);
        a1[i] = fmaf(e, rgbl[576 + ry * 24 + rx], a1[i]);
        a2[i] = fmaf(e, rgbl[1152 + ry * 24 + rx], a2[i]);
      }
    }
    #pragma unroll
    for (int st = 1; st < 16; st <<= 1)
      #pragma unroll
      for (int i = 0; i < 4; ++i) {
        s[i] += __shfl_xor(s[i], st);
        a0[i] += __shfl_xor(a0[i], st);
        a1[i] += __shfl_xor(a1[i], st);
        a2[i] += __shfl_xor(a2[i], st);
      }
    if (n == 0) {
      int y = y0 + ry0;
      #pragma unroll
      for (int i = 0; i < 4; ++i) {
        int x = x0 + q * 4 + i;
        float inv = 1.f / s[i];
        size_t o = (size_t)b * 3 * HWSZ + (size_t)y * WW + x;
        out[o] = a0[i] * inv;
        out[o + HWSZ] = a1[i] * inv;
        out[o + 2 * HWSZ] = a2[i] * inv;
      }
    }
  }
}

extern "C" void kernel_launch(void* const* d_in, const int* in_sizes, int n_in,
                              void* d_out, int out_size, void* d_ws, size_t ws_size,
                              hipStream_t stream) {
  const float* rgb   = (const float*)d_in[0];
  const float* depth = (const float*)d_in[1];
  const float* w1    = (const float*)d_in[2];
  const float* b1    = (const float*)d_in[3];
  const float* w2    = (const float*)d_in[4];
  const float* b2    = (const float*)d_in[5];
  const float* w3    = (const float*)d_in[6];
  const float* b3    = (const float*)d_in[7];
  char* ws = (char*)d_ws;
  unsigned short* h2 = (unsigned short*)d_ws;
  float* out = (float*)d_out;

  prep<<<369, 256, 0, stream>>>(w1, w2, w3, ws);

  dim3 grid(WW / 16, HH / 16, NB);  // 24 x 24 x 4
  conv12<<<grid, 256, 0, stream>>>(rgb, depth, b1, b2, ws, h2);
  conv3bokeh<<<grid, 512, 0, stream>>>(h2, rgb, b3, ws, out);
}

// Round 10
// 425.549 us; speedup vs baseline: 1.1180x; 1.0612x over previous
//
#include <hip/hip_runtime.h>
#include <hip/hip_fp16.h>

#define HH 384
#define WW 384
#define HWSZ (HH*WW)   // 147456
#define NB 4

typedef _Float16 f16x8 __attribute__((ext_vector_type(8)));
typedef float    f32x4 __attribute__((ext_vector_type(4)));

// ---- ws layout (bytes) ----
// h2 fp16 NHWC [4][384][384][64]: 75,497,472 B @ 0
#define W1T_B 75497472u               // [36][64] f32, 9216 B
#define W2F_B (W1T_B + 9216u)         // [2][9][4][64][8] f16, 73728 B  (B-frag order)
#define W3F_B (W2F_B + 73728u)        // [2][9][6][64][8] f16, 110592 B (B-frag order, co pad 96)
// total 75,691,008 B ~= 72.2 MiB (proven safe)

// ---- prep: w1 transpose (f32) + w2/w3 packed into MFMA B-fragment order (f16) ----
// B-frag for 16x16x32: lane l supplies B[k=(l>>4)*8+j][n=l&15]; frag = 64 lanes x 8 halfs.
__global__ __launch_bounds__(256) void prep(const float* __restrict__ w1,
    const float* __restrict__ w2, const float* __restrict__ w3, char* __restrict__ ws) {
  int i = blockIdx.x * 256 + threadIdx.x;
  float* w1T = (float*)(ws + W1T_B);
  _Float16* w2f = (_Float16*)(ws + W2F_B);
  _Float16* w3f = (_Float16*)(ws + W3F_B);
  if (i < 2304) { int co = i & 63, row = i >> 6; w1T[i] = w1[co * 36 + row]; return; }
  int o = i - 2304;
  if (o < 36864) {  // w2f: [cc][tap][cj][lane][j] strides 18432/2048/512/8/1
    int cc = o / 18432, rem = o % 18432;
    int tap = rem >> 11, r2 = rem & 2047;
    int cj = r2 >> 9, l = (r2 >> 3) & 63, j = r2 & 7;
    int co = cj * 16 + (l & 15);
    int ci = cc * 32 + (l >> 4) * 8 + j;
    w2f[o] = (_Float16)w2[co * 576 + ci * 9 + tap];
    return;
  }
  o -= 36864;
  if (o < 55296) {  // w3f: [cc][tap][cj][lane][j] strides 27648/3072/512/8/1
    int cc = o / 27648, rem = o % 27648;
    int tap = rem / 3072, r2 = rem % 3072;
    int cj = r2 >> 9, l = (r2 >> 3) & 63, j = r2 & 7;
    int co = cj * 16 + (l & 15);
    int ci = cc * 32 + (l >> 4) * 8 + j;
    w3f[o] = (co < 81) ? (_Float16)w3[co * 576 + ci * 9 + tap] : (_Float16)0.f;
  }
}

// ---- stage 1: fused conv1 (VALU) + conv2 (MFMA) -> h2 fp16 NHWC ----
// block = 16x16 px, 256 thr = 4 waves; wave w owns output rows w*4..w*4+3, all 64 co.
// Weights staged to LDS per ci-chunk (R9 lesson: B-frags straight from global in the
// MFMA loop are latency-bound at low occupancy — 277 vs 147 us). Staging loads issue
// before conv1's VALU phase and overlap it. NO VGPR min-waves cap (R8: cap -> spill).
__global__ __launch_bounds__(256) void conv12(
    const float* __restrict__ rgb, const float* __restrict__ depth,
    const float* __restrict__ b1, const float* __restrict__ b2,
    const char* __restrict__ wsro, unsigned short* __restrict__ h2) {
  __shared__ __align__(16) char smem[64000];
  float*    xw  = (float*)smem;                 // 6400 B  [4][20][20] origin (-2,-2)
  _Float16* h1T = (_Float16*)(smem + 6400);     // 20736 B [18*18][32] swizzled
  _Float16* w2l = (_Float16*)(smem + 27136);    // 36864 B [tap][cj][lane*8]
  _Float16* tr  = (_Float16*)(smem + 27136);    // epilogue alias of w2l: [16][16][72]
  const int t = threadIdx.x;
  const int x0 = blockIdx.x * 16, y0 = blockIdx.y * 16, b = blockIdx.z;
  const float* w1T = (const float*)(wsro + W1T_B);
  const _Float16* w2f = (const _Float16*)(wsro + W2F_B);
  const int lane = t & 63, q = lane >> 4, n = lane & 15, w = t >> 6;

  // stage input tile
  for (int idx = t; idx < 1600; idx += 256) {
    int ci = idx / 400, r2 = idx % 400, iy = r2 / 20, ix = r2 % 20;
    int gy = y0 + iy - 2, gx = x0 + ix - 2;
    float v = 0.f;
    if ((unsigned)gy < (unsigned)HH && (unsigned)gx < (unsigned)WW)
      v = (ci < 3) ? rgb[(size_t)(b * 3 + ci) * HWSZ + gy * WW + gx]
                   : depth[(size_t)b * HWSZ + gy * WW + gx];
    xw[idx] = v;
  }

  f32x4 acc[4][4];
  #pragma unroll
  for (int cj = 0; cj < 4; ++cj) {
    float bv = b2[cj * 16 + n];
    #pragma unroll
    for (int ri = 0; ri < 4; ++ri) acc[ri][cj] = (f32x4){bv, bv, bv, bv};
  }
  __syncthreads();

  // conv1 work split (balanced): wave w computes co-half h=w>>1 (wave-uniform ->
  // weight reads stay scalar) for px range [(w&1)*162, +162) of the 18x18 halo.
  const int h1h = w >> 1;              // co-half within ci-chunk (0/1)
  const int pxb = (w & 1) * 162;       // px base for this wave

  for (int cc = 0; cc < 2; ++cc) {
    // stage w2 frag chunk into LDS (36864 B contiguous); overlaps conv1 below.
    {
      const float4* src = (const float4*)(w2f + cc * 18432);
      float4* dst = (float4*)w2l;
      for (int idx = t; idx < 2304; idx += 256) dst[idx] = src[idx];
    }
    // conv1: h1 co-chunk [cc*32+h1h*16, +16). OOB positions MUST be zero.
    #pragma unroll 1
    for (int p = 0; p < 3; ++p) {
      int rel = p * 64 + lane;
      if (rel < 162) {
        int px = pxb + rel;
        int row = px / 18, col = px % 18;
        bool ok = ((unsigned)(y0 + row - 1) < (unsigned)HH) &&
                  ((unsigned)(x0 + col - 1) < (unsigned)WW);
        float a1[16];
        #pragma unroll
        for (int k = 0; k < 16; ++k) a1[k] = b1[cc * 32 + h1h * 16 + k];
        #pragma unroll 1
        for (int ci = 0; ci < 4; ++ci) {
          #pragma unroll 1
          for (int ky = 0; ky < 3; ++ky) {
            const float* xp = &xw[ci * 400 + (row + ky) * 20 + col];
            float xv[3] = {xp[0], xp[1], xp[2]};
            #pragma unroll
            for (int kx = 0; kx < 3; ++kx) {
              const float* wr = w1T + (ci * 9 + ky * 3 + kx) * 64 + cc * 32 + h1h * 16;
              #pragma unroll
              for (int k = 0; k < 16; ++k) a1[k] = fmaf(xv[kx], wr[k], a1[k]);
            }
          }
        }
        int base = (row * 18 + col) * 32, sw = col & 3;
        #pragma unroll
        for (int g2 = 0; g2 < 2; ++g2) {
          int g = h1h * 2 + g2;
          f16x8 hv;
          #pragma unroll
          for (int j = 0; j < 8; ++j)
            hv[j] = ok ? (_Float16)fmaxf(a1[g2 * 8 + j], 0.f) : (_Float16)0.f;
          *(f16x8*)&h1T[base + ((g ^ sw) * 8)] = hv;
        }
      }
    }
    __syncthreads();

    // conv2 MFMA: 9 taps x (4 A ds_reads + 4 B ds_reads -> 16 MFMA)
    #pragma unroll 1
    for (int tap = 0; tap < 9; ++tap) {
      int ty = tap / 3, tx = tap % 3;
      f16x8 af[4];
      #pragma unroll
      for (int ri = 0; ri < 4; ++ri) {
        int row = w * 4 + ri + ty;           // 0..17
        int col = n + tx;                    // A-frag m = lane&15 = x
        af[ri] = *(const f16x8*)&h1T[(row * 18 + col) * 32 + ((q ^ (col & 3)) * 8)];
      }
      #pragma unroll
      for (int cj = 0; cj < 4; ++cj) {
        f16x8 bf = *(const f16x8*)&w2l[(tap * 4 + cj) * 512 + lane * 8];
        #pragma unroll
        for (int ri = 0; ri < 4; ++ri)
          acc[ri][cj] = __builtin_amdgcn_mfma_f32_16x16x32_f16(af[ri], bf, acc[ri][cj], 0, 0, 0);
      }
    }
    __syncthreads();
  }

  // epilogue: ReLU + fp16, transpose via LDS (tr aliases dead w2l), NHWC store.
  // D layout: x = q*4+i, co = cj*16+n, y = w*4+ri.
  #pragma unroll
  for (int ri = 0; ri < 4; ++ri) {
    int py = w * 4 + ri;
    #pragma unroll
    for (int cj = 0; cj < 4; ++cj)
      #pragma unroll
      for (int i = 0; i < 4; ++i)
        tr[(py * 16 + q * 4 + i) * 72 + cj * 16 + n] = (_Float16)fmaxf(acc[ri][cj][i], 0.f);
  }
  __syncthreads();
  #pragma unroll
  for (int k = 0; k < 8; ++k) {
    int idx = t + k * 256;                     // [0,2048): y | x | c8
    int y = idx >> 7, x = (idx >> 3) & 15, c8 = (idx & 7) * 8;
    f16x8 v = *(const f16x8*)&tr[(y * 16 + x) * 72 + c8];
    *(f16x8*)&h2[(((size_t)b * HH + y0 + y) * WW + x0 + x) * 64 + c8] = v;
  }
}

// ---- stage 2: conv3 (MFMA, co 81->96) + in-wave softmax + bokeh ----
// block = 16x16 px, 512 thr = 8 waves; wave w owns rows 2w..2w+1 (acc[2][6] = 48 VGPR).
// Weights staged to LDS per 3-tap group (18432 B -> LDS 46080, 3 blocks/CU).
// NOTE: every loop touching acc[][] must be FULLY UNROLLED — a runtime index on
// acc demotes it to scratch (R6: 1.5 GB of scratch churn). NO VGPR cap (R8 lesson).
__global__ __launch_bounds__(512) void conv3bokeh(
    const unsigned short* __restrict__ h2, const float* __restrict__ rgb,
    const float* __restrict__ b3, const char* __restrict__ wsro,
    float* __restrict__ out) {
  __shared__ __align__(16) char smem[46080];
  _Float16* h2T  = (_Float16*)smem;             // 20736 B [18*18][32] swizzled
  _Float16* w3l  = (_Float16*)(smem + 20736);   // 18432 B [tt][cj][lane*8]
  float*    rgbl = (float*)(smem + 39168);      // 6912 B  [3][24][24] origin (-4,-4)
  const int t = threadIdx.x;
  const int x0 = blockIdx.x * 16, y0 = blockIdx.y * 16, b = blockIdx.z;
  const _Float16* w3f = (const _Float16*)(wsro + W3F_B);
  const int lane = t & 63, q = lane >> 4, n = lane & 15, w = t >> 6;

  f32x4 acc[2][6];
  #pragma unroll
  for (int cj = 0; cj < 6; ++cj) {
    int tap = cj * 16 + n;
    float bv = (tap < 81) ? b3[tap] : 0.f;
    acc[0][cj] = (f32x4){bv, bv, bv, bv};
    acc[1][cj] = (f32x4){bv, bv, bv, bv};
  }
  // stage rgb tile
  for (int idx = t; idx < 1728; idx += 512) {
    int c = idx / 576, r2 = idx % 576, ry = r2 / 24, rx = r2 % 24;
    int gy = y0 + ry - 4, gx = x0 + rx - 4;
    float v = 0.f;
    if ((unsigned)gy < (unsigned)HH && (unsigned)gx < (unsigned)WW)
      v = rgb[(size_t)(b * 3 + c) * HWSZ + gy * WW + gx];
    rgbl[idx] = v;
  }

  for (int cc = 0; cc < 2; ++cc) {
    // stage h2T chunk from NHWC h2: 16B-aligned coalesced f16x8 loads, zero-padded.
    for (int idx = t; idx < 1296; idx += 512) {
      int g = idx & 3, pc = idx >> 2;
      int row = pc / 18, col = pc % 18;
      int gy = y0 + row - 1, gx = x0 + col - 1;
      f16x8 v = {};
      if ((unsigned)gy < (unsigned)HH && (unsigned)gx < (unsigned)WW)
        v = *(const f16x8*)&h2[(((size_t)b * HH + gy) * WW + gx) * 64 + cc * 32 + g * 8];
      *(f16x8*)&h2T[(row * 18 + col) * 32 + ((g ^ (col & 3)) * 8)] = v;
    }
    #pragma unroll 1
    for (int tg = 0; tg < 3; ++tg) {
      // stage w3 frag 3-tap group (18432 B contiguous)
      {
        const float4* src = (const float4*)(w3f + cc * 27648 + tg * 9216);
        float4* dst = (float4*)w3l;
        for (int idx = t; idx < 1152; idx += 512) dst[idx] = src[idx];
      }
      __syncthreads();
      #pragma unroll 1
      for (int tt = 0; tt < 3; ++tt) {
        int tap = tg * 3 + tt, ty = tap / 3, tx = tap % 3;
        f16x8 af[2];
        #pragma unroll
        for (int ri = 0; ri < 2; ++ri) {
          int row = w * 2 + ri + ty;           // 0..17
          int col = n + tx;
          af[ri] = *(const f16x8*)&h2T[(row * 18 + col) * 32 + ((q ^ (col & 3)) * 8)];
        }
        #pragma unroll
        for (int cj = 0; cj < 6; ++cj) {
          f16x8 bf = *(const f16x8*)&w3l[(tt * 6 + cj) * 512 + lane * 8];
          acc[0][cj] = __builtin_amdgcn_mfma_f32_16x16x32_f16(af[0], bf, acc[0][cj], 0, 0, 0);
          acc[1][cj] = __builtin_amdgcn_mfma_f32_16x16x32_f16(af[1], bf, acc[1][cj], 0, 0, 0);
        }
      }
      __syncthreads();   // protects w3l (and h2T on last tg) before overwrite
    }
  }

  // epilogue: per-pixel softmax over 81 taps (lanes n=0..15 x cj=0..5) + bokeh gather.
  // FULLY unrolled over ri (see note above).
  int tyj[6], txj[6]; float vm[6];
  #pragma unroll
  for (int cj = 0; cj < 6; ++cj) {
    int tap = cj * 16 + n;
    tyj[cj] = tap / 9; txj[cj] = tap % 9;
    vm[cj] = (tap < 81) ? 1.f : 0.f;
  }
  #pragma unroll
  for (int ri = 0; ri < 2; ++ri) {
    int ry0 = w * 2 + ri;
    float mx[4];
    #pragma unroll
    for (int i = 0; i < 4; ++i) {
      float m = -1e30f;
      #pragma unroll
      for (int cj = 0; cj < 6; ++cj)
        m = fmaxf(m, vm[cj] > 0.f ? acc[ri][cj][i] : -1e30f);
      mx[i] = m;
    }
    #pragma unroll
    for (int st = 1; st < 16; st <<= 1)
      #pragma unroll
      for (int i = 0; i < 4; ++i) mx[i] = fmaxf(mx[i], __shfl_xor(mx[i], st));
    float s[4] = {0, 0, 0, 0}, a0[4] = {0, 0, 0, 0}, a1[4] = {0, 0, 0, 0}, a2[4] = {0, 0, 0, 0};
    #pragma unroll
    for (int cj = 0; cj < 6; ++cj) {
      int ry = ry0 + tyj[cj];
      #pragma unroll
      for (int i = 0; i < 4; ++i) {
        float e = vm[cj] * __expf(acc[ri][cj][i] - mx[i]);
        s[i] += e;
        int rx = q * 4 + i + txj[cj];
        a0[i] = fmaf(e, rgbl[ry * 24 + rx], a0[i]);
        a1[i] = fmaf(e, rgbl[576 + ry * 24 + rx], a1[i]);
        a2[i] = fmaf(e, rgbl[1152 + ry * 24 + rx], a2[i]);
      }
    }
    #pragma unroll
    for (int st = 1; st < 16; st <<= 1)
      #pragma unroll
      for (int i = 0; i < 4; ++i) {
        s[i] += __shfl_xor(s[i], st);
        a0[i] += __shfl_xor(a0[i], st);
        a1[i] += __shfl_xor(a1[i], st);
        a2[i] += __shfl_xor(a2[i], st);
      }
    if (n == 0) {
      int y = y0 + ry0;
      #pragma unroll
      for (int i = 0; i < 4; ++i) {
        int x = x0 + q * 4 + i;
        float inv = 1.f / s[i];
        size_t o = (size_t)b * 3 * HWSZ + (size_t)y * WW + x;
        out[o] = a0[i] * inv;
        out[o + HWSZ] = a1[i] * inv;
        out[o + 2 * HWSZ] = a2[i] * inv;
      }
    }
  }
}

extern "C" void kernel_launch(void* const* d_in, const int* in_sizes, int n_in,
                              void* d_out, int out_size, void* d_ws, size_t ws_size,
                              hipStream_t stream) {
  const float* rgb   = (const float*)d_in[0];
  const float* depth = (const float*)d_in[1];
  const float* w1    = (const float*)d_in[2];
  const float* b1    = (const float*)d_in[3];
  const float* w2    = (const float*)d_in[4];
  const float* b2    = (const float*)d_in[5];
  const float* w3    = (const float*)d_in[6];
  const float* b3    = (const float*)d_in[7];
  char* ws = (char*)d_ws;
  unsigned short* h2 = (unsigned short*)d_ws;
  float* out = (float*)d_out;

  prep<<<369, 256, 0, stream>>>(w1, w2, w3, ws);

  dim3 grid(WW / 16, HH / 16, NB);  // 24 x 24 x 4
  conv12<<<grid, 256, 0, stream>>>(rgb, depth, b1, b2, ws, h2);
  conv3bokeh<<<grid, 512, 0, stream>>>(h2, rgb, b3, ws, out);
}

// Round 11
// 296.620 us; speedup vs baseline: 1.6040x; 1.4347x over previous
//
#include <hip/hip_runtime.h>
#include <hip/hip_fp16.h>

#define HH 384
#define WW 384
#define HWSZ (HH*WW)   // 147456
#define NB 4

typedef _Float16 f16x8 __attribute__((ext_vector_type(8)));
typedef float    f32x4 __attribute__((ext_vector_type(4)));

// ---- ws layout (bytes) ----
// h2 fp16 NHWC [4][384][384][64]: 75,497,472 B @ 0
#define W1T_B 75497472u               // [36][64] f32, 9216 B
#define W2F_B (W1T_B + 9216u)         // [2][9][4][64][8] f16, 73728 B  (B-frag order)
#define W3F_B (W2F_B + 73728u)        // [2][9][6][64][8] f16, 110592 B (B-frag order, co pad 96)
// total 75,691,008 B ~= 72.2 MiB (proven safe)

// ---- prep: w1 transpose (f32) + w2/w3 packed into MFMA B-fragment order (f16) ----
// B-frag for 16x16x32: lane l supplies B[k=(l>>4)*8+j][n=l&15]; frag = 64 lanes x 8 halfs.
__global__ __launch_bounds__(256) void prep(const float* __restrict__ w1,
    const float* __restrict__ w2, const float* __restrict__ w3, char* __restrict__ ws) {
  int i = blockIdx.x * 256 + threadIdx.x;
  float* w1T = (float*)(ws + W1T_B);
  _Float16* w2f = (_Float16*)(ws + W2F_B);
  _Float16* w3f = (_Float16*)(ws + W3F_B);
  if (i < 2304) { int co = i & 63, row = i >> 6; w1T[i] = w1[co * 36 + row]; return; }
  int o = i - 2304;
  if (o < 36864) {  // w2f: [cc][tap][cj][lane][j] strides 18432/2048/512/8/1
    int cc = o / 18432, rem = o % 18432;
    int tap = rem >> 11, r2 = rem & 2047;
    int cj = r2 >> 9, l = (r2 >> 3) & 63, j = r2 & 7;
    int co = cj * 16 + (l & 15);
    int ci = cc * 32 + (l >> 4) * 8 + j;
    w2f[o] = (_Float16)w2[co * 576 + ci * 9 + tap];
    return;
  }
  o -= 36864;
  if (o < 55296) {  // w3f: [cc][tap][cj][lane][j] strides 27648/3072/512/8/1
    int cc = o / 27648, rem = o % 27648;
    int tap = rem / 3072, r2 = rem % 3072;
    int cj = r2 >> 9, l = (r2 >> 3) & 63, j = r2 & 7;
    int co = cj * 16 + (l & 15);
    int ci = cc * 32 + (l >> 4) * 8 + j;
    w3f[o] = (co < 81) ? (_Float16)w3[co * 576 + ci * 9 + tap] : (_Float16)0.f;
  }
}

// ---- stage 1: fused conv1 (VALU) + conv2 (MFMA) -> h2 fp16 NHWC ----
// block = 16x16 px, 256 thr = 4 waves; wave w owns output rows w*4..w*4+3, all 64 co.
// Weights staged to LDS per ci-chunk (R9: global B-frags in the MFMA loop are
// latency-bound). conv1 split is balanced per-wave, with h1h/pxb forced into SGPRs
// via readfirstlane — R9/R10 lesson: a per-wave (but not provably uniform) weight
// address turns conv1's s_load weight reads into ~200-cyc VMEM broadcasts (2x kernel
// time). NO VGPR min-waves cap (R8: cap -> spill).
__global__ __launch_bounds__(256) void conv12(
    const float* __restrict__ rgb, const float* __restrict__ depth,
    const float* __restrict__ b1, const float* __restrict__ b2,
    const char* __restrict__ wsro, unsigned short* __restrict__ h2) {
  __shared__ __align__(16) char smem[64000];
  float*    xw  = (float*)smem;                 // 6400 B  [4][20][20] origin (-2,-2)
  _Float16* h1T = (_Float16*)(smem + 6400);     // 20736 B [18*18][32] swizzled
  _Float16* w2l = (_Float16*)(smem + 27136);    // 36864 B [tap][cj][lane*8]
  _Float16* tr  = (_Float16*)(smem + 27136);    // epilogue alias of w2l: [16][16][72]
  const int t = threadIdx.x;
  const int x0 = blockIdx.x * 16, y0 = blockIdx.y * 16, b = blockIdx.z;
  const float* w1T = (const float*)(wsro + W1T_B);
  const _Float16* w2f = (const _Float16*)(wsro + W2F_B);
  const int lane = t & 63, q = lane >> 4, n = lane & 15, w = t >> 6;

  // stage input tile
  for (int idx = t; idx < 1600; idx += 256) {
    int ci = idx / 400, r2 = idx % 400, iy = r2 / 20, ix = r2 % 20;
    int gy = y0 + iy - 2, gx = x0 + ix - 2;
    float v = 0.f;
    if ((unsigned)gy < (unsigned)HH && (unsigned)gx < (unsigned)WW)
      v = (ci < 3) ? rgb[(size_t)(b * 3 + ci) * HWSZ + gy * WW + gx]
                   : depth[(size_t)b * HWSZ + gy * WW + gx];
    xw[idx] = v;
  }

  f32x4 acc[4][4];
  #pragma unroll
  for (int cj = 0; cj < 4; ++cj) {
    float bv = b2[cj * 16 + n];
    #pragma unroll
    for (int ri = 0; ri < 4; ++ri) acc[ri][cj] = (f32x4){bv, bv, bv, bv};
  }
  __syncthreads();

  // conv1 work split (balanced): wave w computes co-half h1h=w>>1 for px range
  // [(w&1)*162, +162) of the 18x18 halo. readfirstlane -> SGPR -> weight/bias
  // reads stay scalar s_loads.
  const int h1h = __builtin_amdgcn_readfirstlane(w >> 1);   // co-half (0/1)
  const int pxb = __builtin_amdgcn_readfirstlane((w & 1) * 162);

  for (int cc = 0; cc < 2; ++cc) {
    // stage w2 frag chunk into LDS (36864 B contiguous); overlaps conv1 below.
    {
      const float4* src = (const float4*)(w2f + cc * 18432);
      float4* dst = (float4*)w2l;
      for (int idx = t; idx < 2304; idx += 256) dst[idx] = src[idx];
    }
    // conv1: h1 co-chunk [cc*32+h1h*16, +16). OOB positions MUST be zero.
    #pragma unroll 1
    for (int p = 0; p < 3; ++p) {
      int rel = p * 64 + lane;
      if (rel < 162) {
        int px = pxb + rel;
        int row = px / 18, col = px % 18;
        bool ok = ((unsigned)(y0 + row - 1) < (unsigned)HH) &&
                  ((unsigned)(x0 + col - 1) < (unsigned)WW);
        float a1[16];
        #pragma unroll
        for (int k = 0; k < 16; ++k) a1[k] = b1[cc * 32 + h1h * 16 + k];
        #pragma unroll 1
        for (int ci = 0; ci < 4; ++ci) {
          #pragma unroll 1
          for (int ky = 0; ky < 3; ++ky) {
            const float* xp = &xw[ci * 400 + (row + ky) * 20 + col];
            float xv[3] = {xp[0], xp[1], xp[2]};
            #pragma unroll
            for (int kx = 0; kx < 3; ++kx) {
              const float* wr = w1T + (ci * 9 + ky * 3 + kx) * 64 + cc * 32 + h1h * 16;
              #pragma unroll
              for (int k = 0; k < 16; ++k) a1[k] = fmaf(xv[kx], wr[k], a1[k]);
            }
          }
        }
        int base = (row * 18 + col) * 32, sw = col & 3;
        #pragma unroll
        for (int g2 = 0; g2 < 2; ++g2) {
          int g = h1h * 2 + g2;
          f16x8 hv;
          #pragma unroll
          for (int j = 0; j < 8; ++j)
            hv[j] = ok ? (_Float16)fmaxf(a1[g2 * 8 + j], 0.f) : (_Float16)0.f;
          *(f16x8*)&h1T[base + ((g ^ sw) * 8)] = hv;
        }
      }
    }
    __syncthreads();

    // conv2 MFMA: 9 taps x (4 A ds_reads + 4 B ds_reads -> 16 MFMA)
    #pragma unroll 1
    for (int tap = 0; tap < 9; ++tap) {
      int ty = tap / 3, tx = tap % 3;
      f16x8 af[4];
      #pragma unroll
      for (int ri = 0; ri < 4; ++ri) {
        int row = w * 4 + ri + ty;           // 0..17
        int col = n + tx;                    // A-frag m = lane&15 = x
        af[ri] = *(const f16x8*)&h1T[(row * 18 + col) * 32 + ((q ^ (col & 3)) * 8)];
      }
      #pragma unroll
      for (int cj = 0; cj < 4; ++cj) {
        f16x8 bf = *(const f16x8*)&w2l[(tap * 4 + cj) * 512 + lane * 8];
        #pragma unroll
        for (int ri = 0; ri < 4; ++ri)
          acc[ri][cj] = __builtin_amdgcn_mfma_f32_16x16x32_f16(af[ri], bf, acc[ri][cj], 0, 0, 0);
      }
    }
    __syncthreads();
  }

  // epilogue: ReLU + fp16, transpose via LDS (tr aliases dead w2l), NHWC store.
  // D layout: x = q*4+i, co = cj*16+n, y = w*4+ri.
  #pragma unroll
  for (int ri = 0; ri < 4; ++ri) {
    int py = w * 4 + ri;
    #pragma unroll
    for (int cj = 0; cj < 4; ++cj)
      #pragma unroll
      for (int i = 0; i < 4; ++i)
        tr[(py * 16 + q * 4 + i) * 72 + cj * 16 + n] = (_Float16)fmaxf(acc[ri][cj][i], 0.f);
  }
  __syncthreads();
  #pragma unroll
  for (int k = 0; k < 8; ++k) {
    int idx = t + k * 256;                     // [0,2048): y | x | c8
    int y = idx >> 7, x = (idx >> 3) & 15, c8 = (idx & 7) * 8;
    f16x8 v = *(const f16x8*)&tr[(y * 16 + x) * 72 + c8];
    *(f16x8*)&h2[(((size_t)b * HH + y0 + y) * WW + x0 + x) * 64 + c8] = v;
  }
}

// ---- stage 2: conv3 (MFMA, co 81->96) + in-wave softmax + bokeh ----
// block = 16x16 px, 512 thr = 8 waves; wave w owns rows 2w..2w+1 (acc[2][6] = 48 VGPR).
// Weights staged to LDS per 3-tap group (18432 B -> LDS 46080, 3 blocks/CU).
// NOTE: every loop touching acc[][] must be FULLY UNROLLED — a runtime index on
// acc demotes it to scratch (R6: 1.5 GB of scratch churn). NO VGPR cap (R8 lesson).
__global__ __launch_bounds__(512) void conv3bokeh(
    const unsigned short* __restrict__ h2, const float* __restrict__ rgb,
    const float* __restrict__ b3, const char* __restrict__ wsro,
    float* __restrict__ out) {
  __shared__ __align__(16) char smem[46080];
  _Float16* h2T  = (_Float16*)smem;             // 20736 B [18*18][32] swizzled
  _Float16* w3l  = (_Float16*)(smem + 20736);   // 18432 B [tt][cj][lane*8]
  float*    rgbl = (float*)(smem + 39168);      // 6912 B  [3][24][24] origin (-4,-4)
  const int t = threadIdx.x;
  const int x0 = blockIdx.x * 16, y0 = blockIdx.y * 16, b = blockIdx.z;
  const _Float16* w3f = (const _Float16*)(wsro + W3F_B);
  const int lane = t & 63, q = lane >> 4, n = lane & 15, w = t >> 6;

  f32x4 acc[2][6];
  #pragma unroll
  for (int cj = 0; cj < 6; ++cj) {
    int tap = cj * 16 + n;
    float bv = (tap < 81) ? b3[tap] : 0.f;
    acc[0][cj] = (f32x4){bv, bv, bv, bv};
    acc[1][cj] = (f32x4){bv, bv, bv, bv};
  }
  // stage rgb tile
  for (int idx = t; idx < 1728; idx += 512) {
    int c = idx / 576, r2 = idx % 576, ry = r2 / 24, rx = r2 % 24;
    int gy = y0 + ry - 4, gx = x0 + rx - 4;
    float v = 0.f;
    if ((unsigned)gy < (unsigned)HH && (unsigned)gx < (unsigned)WW)
      v = rgb[(size_t)(b * 3 + c) * HWSZ + gy * WW + gx];
    rgbl[idx] = v;
  }

  for (int cc = 0; cc < 2; ++cc) {
    // stage h2T chunk from NHWC h2: 16B-aligned coalesced f16x8 loads, zero-padded.
    for (int idx = t; idx < 1296; idx += 512) {
      int g = idx & 3, pc = idx >> 2;
      int row = pc / 18, col = pc % 18;
      int gy = y0 + row - 1, gx = x0 + col - 1;
      f16x8 v = {};
      if ((unsigned)gy < (unsigned)HH && (unsigned)gx < (unsigned)WW)
        v = *(const f16x8*)&h2[(((size_t)b * HH + gy) * WW + gx) * 64 + cc * 32 + g * 8];
      *(f16x8*)&h2T[(row * 18 + col) * 32 + ((g ^ (col & 3)) * 8)] = v;
    }
    #pragma unroll 1
    for (int tg = 0; tg < 3; ++tg) {
      // stage w3 frag 3-tap group (18432 B contiguous)
      {
        const float4* src = (const float4*)(w3f + cc * 27648 + tg * 9216);
        float4* dst = (float4*)w3l;
        for (int idx = t; idx < 1152; idx += 512) dst[idx] = src[idx];
      }
      __syncthreads();
      #pragma unroll 1
      for (int tt = 0; tt < 3; ++tt) {
        int tap = tg * 3 + tt, ty = tap / 3, tx = tap % 3;
        f16x8 af[2];
        #pragma unroll
        for (int ri = 0; ri < 2; ++ri) {
          int row = w * 2 + ri + ty;           // 0..17
          int col = n + tx;
          af[ri] = *(const f16x8*)&h2T[(row * 18 + col) * 32 + ((q ^ (col & 3)) * 8)];
        }
        #pragma unroll
        for (int cj = 0; cj < 6; ++cj) {
          f16x8 bf = *(const f16x8*)&w3l[(tt * 6 + cj) * 512 + lane * 8];
          acc[0][cj] = __builtin_amdgcn_mfma_f32_16x16x32_f16(af[0], bf, acc[0][cj], 0, 0, 0);
          acc[1][cj] = __builtin_amdgcn_mfma_f32_16x16x32_f16(af[1], bf, acc[1][cj], 0, 0, 0);
        }
      }
      __syncthreads();   // protects w3l (and h2T on last tg) before overwrite
    }
  }

  // epilogue: per-pixel softmax over 81 taps (lanes n=0..15 x cj=0..5) + bokeh gather.
  // FULLY unrolled over ri (see note above).
  int tyj[6], txj[6]; float vm[6];
  #pragma unroll
  for (int cj = 0; cj < 6; ++cj) {
    int tap = cj * 16 + n;
    tyj[cj] = tap / 9; txj[cj] = tap % 9;
    vm[cj] = (tap < 81) ? 1.f : 0.f;
  }
  #pragma unroll
  for (int ri = 0; ri < 2; ++ri) {
    int ry0 = w * 2 + ri;
    float mx[4];
    #pragma unroll
    for (int i = 0; i < 4; ++i) {
      float m = -1e30f;
      #pragma unroll
      for (int cj = 0; cj < 6; ++cj)
        m = fmaxf(m, vm[cj] > 0.f ? acc[ri][cj][i] : -1e30f);
      mx[i] = m;
    }
    #pragma unroll
    for (int st = 1; st < 16; st <<= 1)
      #pragma unroll
      for (int i = 0; i < 4; ++i) mx[i] = fmaxf(mx[i], __shfl_xor(mx[i], st));
    float s[4] = {0, 0, 0, 0}, a0[4] = {0, 0, 0, 0}, a1[4] = {0, 0, 0, 0}, a2[4] = {0, 0, 0, 0};
    #pragma unroll
    for (int cj = 0; cj < 6; ++cj) {
      int ry = ry0 + tyj[cj];
      #pragma unroll
      for (int i = 0; i < 4; ++i) {
        float e = vm[cj] * __expf(acc[ri][cj][i] - mx[i]);
        s[i] += e;
        int rx = q * 4 + i + txj[cj];
        a0[i] = fmaf(e, rgbl[ry * 24 + rx], a0[i]);
        a1[i] = fmaf(e, rgbl[576 + ry * 24 + rx], a1[i]);
        a2[i] = fmaf(e, rgbl[1152 + ry * 24 + rx], a2[i]);
      }
    }
    #pragma unroll
    for (int st = 1; st < 16; st <<= 1)
      #pragma unroll
      for (int i = 0; i < 4; ++i) {
        s[i] += __shfl_xor(s[i], st);
        a0[i] += __shfl_xor(a0[i], st);
        a1[i] += __shfl_xor(a1[i], st);
        a2[i] += __shfl_xor(a2[i], st);
      }
    if (n == 0) {
      int y = y0 + ry0;
      #pragma unroll
      for (int i = 0; i < 4; ++i) {
        int x = x0 + q * 4 + i;
        float inv = 1.f / s[i];
        size_t o = (size_t)b * 3 * HWSZ + (size_t)y * WW + x;
        out[o] = a0[i] * inv;
        out[o + HWSZ] = a1[i] * inv;
        out[o + 2 * HWSZ] = a2[i] * inv;
      }
    }
  }
}

extern "C" void kernel_launch(void* const* d_in, const int* in_sizes, int n_in,
                              void* d_out, int out_size, void* d_ws, size_t ws_size,
                              hipStream_t stream) {
  const float* rgb   = (const float*)d_in[0];
  const float* depth = (const float*)d_in[1];
  const float* w1    = (const float*)d_in[2];
  const float* b1    = (const float*)d_in[3];
  const float* w2    = (const float*)d_in[4];
  const float* b2    = (const float*)d_in[5];
  const float* w3    = (const float*)d_in[6];
  const float* b3    = (const float*)d_in[7];
  char* ws = (char*)d_ws;
  unsigned short* h2 = (unsigned short*)d_ws;
  float* out = (float*)d_out;

  prep<<<369, 256, 0, stream>>>(w1, w2, w3, ws);

  dim3 grid(WW / 16, HH / 16, NB);  // 24 x 24 x 4
  conv12<<<grid, 256, 0, stream>>>(rgb, depth, b1, b2, ws, h2);
  conv3bokeh<<<grid, 512, 0, stream>>>(h2, rgb, b3, ws, out);
}

// Round 12
// 259.731 us; speedup vs baseline: 1.8318x; 1.1420x over previous
//
#include <hip/hip_runtime.h>
#include <hip/hip_fp16.h>

#define HH 384
#define WW 384
#define HWSZ (HH*WW)   // 147456
#define NB 4

typedef _Float16 f16x8 __attribute__((ext_vector_type(8)));
typedef _Float16 f16x2 __attribute__((ext_vector_type(2)));
typedef float    f32x4 __attribute__((ext_vector_type(4)));

// ---- ws layout (bytes) ----
// h2 fp16 NHWC [4][384][384][64]: 75,497,472 B @ 0
#define W1P_B 75497472u               // [9 tap][2 cipair][64 co] f16x2, 4608 B
#define W2F_B (W1P_B + 9216u)         // [2][9][4][64][8] f16, 73728 B  (B-frag order)
#define W3F_B (W2F_B + 73728u)        // [2][9][6][64][8] f16, 110592 B (B-frag order, co pad 96)
// total 75,691,008 B ~= 72.2 MiB (proven safe)

// ---- prep: w1 packed as fp16 ci-pairs + w2/w3 packed into MFMA B-fragment order ----
// B-frag for 16x16x32: lane l supplies B[k=(l>>4)*8+j][n=l&15]; frag = 64 lanes x 8 halfs.
__global__ __launch_bounds__(256) void prep(const float* __restrict__ w1,
    const float* __restrict__ w2, const float* __restrict__ w3, char* __restrict__ ws) {
  int i = blockIdx.x * 256 + threadIdx.x;
  _Float16* w1p = (_Float16*)(ws + W1P_B);
  _Float16* w2f = (_Float16*)(ws + W2F_B);
  _Float16* w3f = (_Float16*)(ws + W3F_B);
  if (i < 2304) {  // w1p linear: tap*256 + cip*128 + co*2 + h ; ci = cip*2+h
    int tap = i >> 8, r = i & 255, cip = r >> 7, rr = r & 127, co = rr >> 1, h = rr & 1;
    w1p[i] = (_Float16)w1[co * 36 + (cip * 2 + h) * 9 + tap];
    return;
  }
  int o = i - 2304;
  if (o < 36864) {  // w2f: [cc][tap][cj][lane][j] strides 18432/2048/512/8/1
    int cc = o / 18432, rem = o % 18432;
    int tap = rem >> 11, r2 = rem & 2047;
    int cj = r2 >> 9, l = (r2 >> 3) & 63, j = r2 & 7;
    int co = cj * 16 + (l & 15);
    int ci = cc * 32 + (l >> 4) * 8 + j;
    w2f[o] = (_Float16)w2[co * 576 + ci * 9 + tap];
    return;
  }
  o -= 36864;
  if (o < 55296) {  // w3f: [cc][tap][cj][lane][j] strides 27648/3072/512/8/1
    int cc = o / 27648, rem = o % 27648;
    int tap = rem / 3072, r2 = rem % 3072;
    int cj = r2 >> 9, l = (r2 >> 3) & 63, j = r2 & 7;
    int co = cj * 16 + (l & 15);
    int ci = cc * 32 + (l >> 4) * 8 + j;
    w3f[o] = (co < 81) ? (_Float16)w3[co * 576 + ci * 9 + tap] : (_Float16)0.f;
  }
}

// ---- stage 1: fused conv1 (fdot2 VALU) + conv2 (MFMA) -> h2 fp16 NHWC ----
// block = 16x16 px, 256 thr = 4 waves; wave w owns output rows w*4..w*4+3, all 64 co.
// conv1: x staged as fp16 ci-pairs, v_dot2_f32_f16 halves VALU ops vs scalar fma.
// conv2: w2 staged to LDS per 3-tap group (12288 B) -> LDS 36864 total, 4 blocks/CU.
// tg0's staging issues BEFORE conv1 so its global latency hides under conv1 VALU.
// Lessons encoded: h1h/pxb via readfirstlane (R10: per-wave addr -> VMEM broadcast,
// 2x); no VGPR min-waves cap (R8: cap -> spill); acc loops fully unrolled (R6).
__global__ __launch_bounds__(256) void conv12(
    const float* __restrict__ rgb, const float* __restrict__ depth,
    const float* __restrict__ b1, const float* __restrict__ b2,
    const char* __restrict__ wsro, unsigned short* __restrict__ h2) {
  __shared__ __align__(16) char smem[36864];
  f16x2*    xwh = (f16x2*)smem;                 // 3200 B  [2 cip][20][20] origin (-2,-2)
  _Float16* h1T = (_Float16*)(smem + 3200);     // 20736 B [18*18][32] swizzled
  _Float16* w2l = (_Float16*)(smem + 23936);    // 12288 B [tt][cj][lane*8] (3-tap group)
  _Float16* tr  = (_Float16*)smem;              // epilogue alias: [16][16][72] = 36864 B
  const int t = threadIdx.x;
  const int x0 = blockIdx.x * 16, y0 = blockIdx.y * 16, b = blockIdx.z;
  const f16x2* w1p = (const f16x2*)(wsro + W1P_B);
  const _Float16* w2f = (const _Float16*)(wsro + W2F_B);
  const int lane = t & 63, q = lane >> 4, n = lane & 15, w = t >> 6;

  // stage input tile as ci-pairs: pair0=(r,g), pair1=(b,depth)
  for (int idx = t; idx < 800; idx += 256) {
    int p = idx / 400, r2 = idx % 400, iy = r2 / 20, ix = r2 % 20;
    int gy = y0 + iy - 2, gx = x0 + ix - 2;
    f16x2 v = {(_Float16)0.f, (_Float16)0.f};
    if ((unsigned)gy < (unsigned)HH && (unsigned)gx < (unsigned)WW) {
      size_t off = (size_t)gy * WW + gx;
      int c0 = p * 2;
      float f0 = rgb[(size_t)(b * 3 + c0) * HWSZ + off];             // c0 = 0 or 2
      float f1 = (c0 + 1 < 3) ? rgb[(size_t)(b * 3 + c0 + 1) * HWSZ + off]
                              : depth[(size_t)b * HWSZ + off];
      v[0] = (_Float16)f0; v[1] = (_Float16)f1;
    }
    xwh[idx] = v;
  }

  f32x4 acc[4][4];
  #pragma unroll
  for (int cj = 0; cj < 4; ++cj) {
    float bv = b2[cj * 16 + n];
    #pragma unroll
    for (int ri = 0; ri < 4; ++ri) acc[ri][cj] = (f32x4){bv, bv, bv, bv};
  }
  __syncthreads();

  // conv1 split: wave w -> co-half h1h=w>>1, px range [(w&1)*162,+162) of 18x18 halo.
  const int h1h = __builtin_amdgcn_readfirstlane(w >> 1);
  const int pxb = __builtin_amdgcn_readfirstlane((w & 1) * 162);

  for (int cc = 0; cc < 2; ++cc) {
    // stage w2 tap-group 0 (issues before conv1; latency hides under conv1 VALU)
    {
      const float4* src = (const float4*)(w2f + cc * 18432);
      float4* dst = (float4*)w2l;
      for (int idx = t; idx < 768; idx += 256) dst[idx] = src[idx];
    }
    // conv1: h1 co-chunk [cc*32+h1h*16, +16). OOB positions MUST be zero.
    #pragma unroll 1
    for (int p = 0; p < 3; ++p) {
      int rel = p * 64 + lane;
      if (rel < 162) {
        int px = pxb + rel;
        int row = px / 18, col = px % 18;
        bool ok = ((unsigned)(y0 + row - 1) < (unsigned)HH) &&
                  ((unsigned)(x0 + col - 1) < (unsigned)WW);
        float a1[16];
        #pragma unroll
        for (int k = 0; k < 16; ++k) a1[k] = b1[cc * 32 + h1h * 16 + k];
        #pragma unroll
        for (int ky = 0; ky < 3; ++ky) {
          const f16x2* xA = &xwh[(row + ky) * 20 + col];
          const f16x2* xB = &xwh[400 + (row + ky) * 20 + col];
          f16x2 xa[3] = {xA[0], xA[1], xA[2]};
          f16x2 xb[3] = {xB[0], xB[1], xB[2]};
          #pragma unroll
          for (int kx = 0; kx < 3; ++kx) {
            int tap = ky * 3 + kx;
            const f16x2* wA = w1p + (tap * 2 + 0) * 64 + cc * 32 + h1h * 16;  // uniform
            const f16x2* wB = w1p + (tap * 2 + 1) * 64 + cc * 32 + h1h * 16;  // uniform
            #pragma unroll
            for (int k = 0; k < 16; ++k) {
              a1[k] = __builtin_amdgcn_fdot2(xa[kx], wA[k], a1[k], false);
              a1[k] = __builtin_amdgcn_fdot2(xb[kx], wB[k], a1[k], false);
            }
          }
        }
        int base = (row * 18 + col) * 32, sw = col & 3;
        #pragma unroll
        for (int g2 = 0; g2 < 2; ++g2) {
          int g = h1h * 2 + g2;
          f16x8 hv;
          #pragma unroll
          for (int j = 0; j < 8; ++j)
            hv[j] = ok ? (_Float16)fmaxf(a1[g2 * 8 + j], 0.f) : (_Float16)0.f;
          *(f16x8*)&h1T[base + ((g ^ sw) * 8)] = hv;
        }
      }
    }
    __syncthreads();

    // conv2 MFMA in 3 tap-groups (ty = tg, tx = tt); w2l re-staged between groups.
    #pragma unroll 1
    for (int tg = 0; tg < 3; ++tg) {
      #pragma unroll
      for (int tt = 0; tt < 3; ++tt) {
        f16x8 af[4];
        #pragma unroll
        for (int ri = 0; ri < 4; ++ri) {
          int row = w * 4 + ri + tg;           // 0..17
          int col = n + tt;                    // A-frag m = lane&15 = x
          af[ri] = *(const f16x8*)&h1T[(row * 18 + col) * 32 + ((q ^ (col & 3)) * 8)];
        }
        #pragma unroll
        for (int cj = 0; cj < 4; ++cj) {
          f16x8 bf = *(const f16x8*)&w2l[(tt * 4 + cj) * 512 + lane * 8];
          #pragma unroll
          for (int ri = 0; ri < 4; ++ri)
            acc[ri][cj] = __builtin_amdgcn_mfma_f32_16x16x32_f16(af[ri], bf, acc[ri][cj], 0, 0, 0);
        }
      }
      __syncthreads();                          // all waves done reading w2l group tg
      if (tg < 2) {
        const float4* src = (const float4*)(w2f + cc * 18432 + (tg + 1) * 6144);
        float4* dst = (float4*)w2l;
        for (int idx = t; idx < 768; idx += 256) dst[idx] = src[idx];
        __syncthreads();
      }
    }
  }

  // epilogue: ReLU + fp16, transpose via LDS (tr aliases all of smem), NHWC store.
  // D layout: x = q*4+i, co = cj*16+n, y = w*4+ri.
  #pragma unroll
  for (int ri = 0; ri < 4; ++ri) {
    int py = w * 4 + ri;
    #pragma unroll
    for (int cj = 0; cj < 4; ++cj)
      #pragma unroll
      for (int i = 0; i < 4; ++i)
        tr[(py * 16 + q * 4 + i) * 72 + cj * 16 + n] = (_Float16)fmaxf(acc[ri][cj][i], 0.f);
  }
  __syncthreads();
  #pragma unroll
  for (int k = 0; k < 8; ++k) {
    int idx = t + k * 256;                     // [0,2048): y | x | c8
    int y = idx >> 7, x = (idx >> 3) & 15, c8 = (idx & 7) * 8;
    f16x8 v = *(const f16x8*)&tr[(y * 16 + x) * 72 + c8];
    *(f16x8*)&h2[(((size_t)b * HH + y0 + y) * WW + x0 + x) * 64 + c8] = v;
  }
}

// ---- stage 2: conv3 (MFMA, co 81->96) + in-wave softmax + bokeh ----
// block = 16x16 px, 512 thr = 8 waves; wave w owns rows 2w..2w+1 (acc[2][6] = 48 VGPR).
// Weights staged to LDS per 3-tap group (18432 B -> LDS 46080, 3 blocks/CU).
// NOTE: every loop touching acc[][] must be FULLY UNROLLED — a runtime index on
// acc demotes it to scratch (R6: 1.5 GB of scratch churn). NO VGPR cap (R8 lesson).
__global__ __launch_bounds__(512) void conv3bokeh(
    const unsigned short* __restrict__ h2, const float* __restrict__ rgb,
    const float* __restrict__ b3, const char* __restrict__ wsro,
    float* __restrict__ out) {
  __shared__ __align__(16) char smem[46080];
  _Float16* h2T  = (_Float16*)smem;             // 20736 B [18*18][32] swizzled
  _Float16* w3l  = (_Float16*)(smem + 20736);   // 18432 B [tt][cj][lane*8]
  float*    rgbl = (float*)(smem + 39168);      // 6912 B  [3][24][24] origin (-4,-4)
  const int t = threadIdx.x;
  const int x0 = blockIdx.x * 16, y0 = blockIdx.y * 16, b = blockIdx.z;
  const _Float16* w3f = (const _Float16*)(wsro + W3F_B);
  const int lane = t & 63, q = lane >> 4, n = lane & 15, w = t >> 6;

  f32x4 acc[2][6];
  #pragma unroll
  for (int cj = 0; cj < 6; ++cj) {
    int tap = cj * 16 + n;
    float bv = (tap < 81) ? b3[tap] : 0.f;
    acc[0][cj] = (f32x4){bv, bv, bv, bv};
    acc[1][cj] = (f32x4){bv, bv, bv, bv};
  }
  // stage rgb tile
  for (int idx = t; idx < 1728; idx += 512) {
    int c = idx / 576, r2 = idx % 576, ry = r2 / 24, rx = r2 % 24;
    int gy = y0 + ry - 4, gx = x0 + rx - 4;
    float v = 0.f;
    if ((unsigned)gy < (unsigned)HH && (unsigned)gx < (unsigned)WW)
      v = rgb[(size_t)(b * 3 + c) * HWSZ + gy * WW + gx];
    rgbl[idx] = v;
  }

  for (int cc = 0; cc < 2; ++cc) {
    // stage h2T chunk from NHWC h2: 16B-aligned coalesced f16x8 loads, zero-padded.
    for (int idx = t; idx < 1296; idx += 512) {
      int g = idx & 3, pc = idx >> 2;
      int row = pc / 18, col = pc % 18;
      int gy = y0 + row - 1, gx = x0 + col - 1;
      f16x8 v = {};
      if ((unsigned)gy < (unsigned)HH && (unsigned)gx < (unsigned)WW)
        v = *(const f16x8*)&h2[(((size_t)b * HH + gy) * WW + gx) * 64 + cc * 32 + g * 8];
      *(f16x8*)&h2T[(row * 18 + col) * 32 + ((g ^ (col & 3)) * 8)] = v;
    }
    #pragma unroll 1
    for (int tg = 0; tg < 3; ++tg) {
      // stage w3 frag 3-tap group (18432 B contiguous)
      {
        const float4* src = (const float4*)(w3f + cc * 27648 + tg * 9216);
        float4* dst = (float4*)w3l;
        for (int idx = t; idx < 1152; idx += 512) dst[idx] = src[idx];
      }
      __syncthreads();
      #pragma unroll
      for (int tt = 0; tt < 3; ++tt) {
        int tap = tg * 3 + tt, ty = tap / 3, tx = tap % 3;
        f16x8 af[2];
        #pragma unroll
        for (int ri = 0; ri < 2; ++ri) {
          int row = w * 2 + ri + ty;           // 0..17
          int col = n + tx;
          af[ri] = *(const f16x8*)&h2T[(row * 18 + col) * 32 + ((q ^ (col & 3)) * 8)];
        }
        #pragma unroll
        for (int cj = 0; cj < 6; ++cj) {
          f16x8 bf = *(const f16x8*)&w3l[(tt * 6 + cj) * 512 + lane * 8];
          acc[0][cj] = __builtin_amdgcn_mfma_f32_16x16x32_f16(af[0], bf, acc[0][cj], 0, 0, 0);
          acc[1][cj] = __builtin_amdgcn_mfma_f32_16x16x32_f16(af[1], bf, acc[1][cj], 0, 0, 0);
        }
      }
      __syncthreads();   // protects w3l (and h2T on last tg) before overwrite
    }
  }

  // epilogue: per-pixel softmax over 81 taps (lanes n=0..15 x cj=0..5) + bokeh gather.
  // FULLY unrolled over ri (see note above).
  int tyj[6], txj[6]; float vm[6];
  #pragma unroll
  for (int cj = 0; cj < 6; ++cj) {
    int tap = cj * 16 + n;
    tyj[cj] = tap / 9; txj[cj] = tap % 9;
    vm[cj] = (tap < 81) ? 1.f : 0.f;
  }
  #pragma unroll
  for (int ri = 0; ri < 2; ++ri) {
    int ry0 = w * 2 + ri;
    float mx[4];
    #pragma unroll
    for (int i = 0; i < 4; ++i) {
      float m = -1e30f;
      #pragma unroll
      for (int cj = 0; cj < 6; ++cj)
        m = fmaxf(m, vm[cj] > 0.f ? acc[ri][cj][i] : -1e30f);
      mx[i] = m;
    }
    #pragma unroll
    for (int st = 1; st < 16; st <<= 1)
      #pragma unroll
      for (int i = 0; i < 4; ++i) mx[i] = fmaxf(mx[i], __shfl_xor(mx[i], st));
    float s[4] = {0, 0, 0, 0}, a0[4] = {0, 0, 0, 0}, a1[4] = {0, 0, 0, 0}, a2[4] = {0, 0, 0, 0};
    #pragma unroll
    for (int cj = 0; cj < 6; ++cj) {
      int ry = ry0 + tyj[cj];
      #pragma unroll
      for (int i = 0; i < 4; ++i) {
        float e = vm[cj] * __expf(acc[ri][cj][i] - mx[i]);
        s[i] += e;
        int rx = q * 4 + i + txj[cj];
        a0[i] = fmaf(e, rgbl[ry * 24 + rx], a0[i]);
        a1[i] = fmaf(e, rgbl[576 + ry * 24 + rx], a1[i]);
        a2[i] = fmaf(e, rgbl[1152 + ry * 24 + rx], a2[i]);
      }
    }
    #pragma unroll
    for (int st = 1; st < 16; st <<= 1)
      #pragma unroll
      for (int i = 0; i < 4; ++i) {
        s[i] += __shfl_xor(s[i], st);
        a0[i] += __shfl_xor(a0[i], st);
        a1[i] += __shfl_xor(a1[i], st);
        a2[i] += __shfl_xor(a2[i], st);
      }
    if (n == 0) {
      int y = y0 + ry0;
      #pragma unroll
      for (int i = 0; i < 4; ++i) {
        int x = x0 + q * 4 + i;
        float inv = 1.f / s[i];
        size_t o = (size_t)b * 3 * HWSZ + (size_t)y * WW + x;
        out[o] = a0[i] * inv;
        out[o + HWSZ] = a1[i] * inv;
        out[o + 2 * HWSZ] = a2[i] * inv;
      }
    }
  }
}

extern "C" void kernel_launch(void* const* d_in, const int* in_sizes, int n_in,
                              void* d_out, int out_size, void* d_ws, size_t ws_size,
                              hipStream_t stream) {
  const float* rgb   = (const float*)d_in[0];
  const float* depth = (const float*)d_in[1];
  const float* w1    = (const float*)d_in[2];
  const float* b1    = (const float*)d_in[3];
  const float* w2    = (const float*)d_in[4];
  const float* b2    = (const float*)d_in[5];
  const float* w3    = (const float*)d_in[6];
  const float* b3    = (const float*)d_in[7];
  char* ws = (char*)d_ws;
  unsigned short* h2 = (unsigned short*)d_ws;
  float* out = (float*)d_out;

  prep<<<369, 256, 0, stream>>>(w1, w2, w3, ws);

  dim3 grid(WW / 16, HH / 16, NB);  // 24 x 24 x 4
  conv12<<<grid, 256, 0, stream>>>(rgb, depth, b1, b2, ws, h2);
  conv3bokeh<<<grid, 512, 0, stream>>>(h2, rgb, b3, ws, out);
}